// Round 7
// baseline (659.219 us; speedup 1.0000x reference)
//
#include <hip/hip_runtime.h>
#include <hip/hip_bf16.h>
#include <hip/hip_cooperative_groups.h>

namespace cg = cooperative_groups;

#define H 128
#define BK 64
#define LDSTR 72   // LDS row stride (f16 elems): 144B, 16B-aligned rows

#define EPB 4096        // edges per block, bucket passes
#define BUCK_BITS 8
#define BUCK 256        // nodes per bucket

typedef _Float16 f16;
typedef unsigned int u32;
typedef __attribute__((ext_vector_type(8))) _Float16 f16x8;
typedef __attribute__((ext_vector_type(4))) _Float16 f16x4;
typedef __attribute__((ext_vector_type(4))) float floatx4;

static inline __host__ int ceil_div(int a, int b) { return (a + b - 1) / b; }

// ======== prepK: entire prep pipeline in ONE cooperative kernel ========
// phase1: per-block histograms (dst>>8, src>>8) + weight transposes   (= old p1K)
// phase2a/2b/2c: 3-level exclusive scan of ch[0..nScan)               (= old scan1/2/3K)
// phase3: scatter edges into bucket-ordered binned[]                  (= old p3K)
// phase4: per-bucket CSR build (rowptr/esrc/norm_d) + norm_s          (= old p4K)
struct PrepArgs {
    const int *sA, *dA; int EA, nblkA, nbinsA;
    const int *sB, *dB; int EB, nblkB, nbinsB;
    int* ch; int offAd, offBd, offAs, offBs, Lall;
    const float* Wa0; f16* ta0; const float* Wa1; f16* ta1;
    const float* Wb0; f16* tb0; const float* Wb1; f16* tb1; int DA;
    int nScan, sb1; int* bsum;
    u32* binned;
    int* rpA; float* ndA; int* esA; int NA;
    int* rpB; float* ndB; int* esB; int NB;
    float* nsA; float* nsB;
    int p1n, wcB, ndst2;
};

__global__ __launch_bounds__(256) void prepK(PrepArgs a) {
    cg::grid_group grid = cg::this_grid();
    __shared__ int sm0[256], sm1[256], sm2[256], sm3[256];
    int bid = blockIdx.x, t = threadIdx.x;

    // ---------------- phase 1: histograms | weight transpose ----------------
    if (bid < a.p1n) {
        const int *src, *dst; int E, nblk, nbins, blk, od, os;
        if (bid < a.nblkA) { src = a.sA; dst = a.dA; E = a.EA; nblk = a.nblkA; nbins = a.nbinsA; blk = bid; od = a.offAd; os = a.offAs; }
        else { src = a.sB; dst = a.dB; E = a.EB; nblk = a.nblkB; nbins = a.nbinsB; blk = bid - a.nblkA; od = a.offBd; os = a.offBs; }
        sm0[t] = 0; sm1[t] = 0;
        __syncthreads();
        int e0 = blk * EPB, e1 = min(E, e0 + EPB);
        for (int e = e0 + t; e < e1; e += 256) {
            atomicAdd(&sm0[dst[e] >> BUCK_BITS], 1);
            atomicAdd(&sm1[src[e] >> BUCK_BITS], 1);
        }
        __syncthreads();
        for (int b = t; b < nbins; b += 256) {
            a.ch[od + b * nblk + blk] = sm0[b];
            a.ch[os + b * nblk + blk] = sm1[b];
        }
        if (bid == 0 && t == 0) a.ch[a.Lall] = 0;   // sentinel
    } else if (bid < a.p1n + a.wcB) {
        int b2 = bid - a.p1n;                        // weight transpose: 2 k-rows per block
        int k2 = b2 * 2 + (t >> 7);
        const float* W; f16* T; int D, k;
        if (k2 < a.DA) { W = a.Wa0; T = a.ta0; D = a.DA; k = k2; }
        else if (k2 < a.DA + H) { W = a.Wa1; T = a.ta1; D = H; k = k2 - a.DA; }
        else if (k2 < a.DA + 2 * H) { W = a.Wb0; T = a.tb0; D = H; k = k2 - a.DA - H; }
        else { W = a.Wb1; T = a.tb1; D = H; k = k2 - a.DA - 2 * H; }
        int c = t & 127;
        T[(size_t)c * D + k] = (f16)W[(size_t)k * H + c];
    }
    grid.sync();

    // ---------------- phase 2a: per-1024-chunk scan ----------------
    if (bid < a.sb1) {
        int base = bid * 1024 + t * 4;
        int v[4];
#pragma unroll
        for (int i = 0; i < 4; i++) v[i] = (base + i < a.nScan) ? a.ch[base + i] : 0;
        int s = v[0] + v[1] + v[2] + v[3];
        sm0[t] = s;
        __syncthreads();
        for (int off = 1; off < 256; off <<= 1) {
            int x = (t >= off) ? sm0[t - off] : 0;
            __syncthreads();
            sm0[t] += x;
            __syncthreads();
        }
        int run = sm0[t] - s;
#pragma unroll
        for (int i = 0; i < 4; i++) {
            if (base + i < a.nScan) a.ch[base + i] = run;
            run += v[i];
        }
        if (t == 255) a.bsum[bid] = sm0[255];
    }
    grid.sync();

    // ---------------- phase 2b: scan of block sums (block 0) ----------------
    if (bid == 0) {
        int v = (t < a.sb1) ? a.bsum[t] : 0;
        sm0[t] = v;
        __syncthreads();
        for (int off = 1; off < 256; off <<= 1) {
            int x = (t >= off) ? sm0[t - off] : 0;
            __syncthreads();
            sm0[t] += x;
            __syncthreads();
        }
        if (t < a.sb1) a.bsum[t] = sm0[t] - v;
    }
    grid.sync();

    // ---------------- phase 2c: add block offsets ----------------
    {
        int i = bid * 256 + t;
        if (i < a.nScan) a.ch[i] += a.bsum[i >> 10];
    }
    grid.sync();

    // ---------------- phase 3: scatter into binned ----------------
    if (bid < a.p1n) {
        const int *src, *dst; int E, nblk, nbins, blk, od, os;
        if (bid < a.nblkA) {
            src = a.sA; dst = a.dA; E = a.EA; nblk = a.nblkA; nbins = a.nbinsA; blk = bid; od = a.offAd; os = a.offAs;
        } else {
            src = a.sB; dst = a.dB; E = a.EB; nblk = a.nblkB; nbins = a.nbinsB; blk = bid - a.nblkA; od = a.offBd; os = a.offBs;
        }
        sm0[t] = 0; sm1[t] = 0;              // cd, cs
        if (t < nbins) {
            sm2[t] = a.ch[od + t * nblk + blk];   // ofd
            sm3[t] = a.ch[os + t * nblk + blk];   // ofs
        }
        __syncthreads();
        int e0 = blk * EPB, e1 = min(E, e0 + EPB);
        for (int e = e0 + t; e < e1; e += 256) {
            int d = dst[e], s = src[e];
            int b = d >> BUCK_BITS;
            int r = atomicAdd(&sm0[b], 1);
            a.binned[sm2[b] + r] = (u32)s | ((u32)(d & (BUCK - 1)) << 16);
            int b2 = s >> BUCK_BITS;
            int r2 = atomicAdd(&sm1[b2], 1);
            a.binned[sm3[b2] + r2] = (u32)(s & (BUCK - 1));
        }
    }
    grid.sync();

    // ---------------- phase 4: per-bucket fine pass ----------------
    int ndst = a.nbinsA + a.nbinsB;
    if (bid == 0 && t == 0) { a.rpA[a.NA] = a.EA; a.rpB[a.NB] = a.EB; }
    if (bid < ndst) {
        // dst bucket: full CSR
        int blk, offm, nblkm, N, ebase; int* rp; float* nd; int* es;
        if (bid < a.nbinsA) { blk = bid; offm = a.offAd; nblkm = a.nblkA; rp = a.rpA; nd = a.ndA; es = a.esA; N = a.NA; ebase = 0; }
        else { blk = bid - a.nbinsA; offm = a.offBd; nblkm = a.nblkB; rp = a.rpB; nd = a.ndB; es = a.esB; N = a.NB; ebase = a.EA; }
        int e0 = a.ch[offm + blk * nblkm];
        int e1 = a.ch[offm + (blk + 1) * nblkm];
        sm0[t] = 0; sm2[t] = 0;              // cnt, fill
        __syncthreads();
        for (int e = e0 + t; e < e1; e += 256) atomicAdd(&sm0[(a.binned[e] >> 16) & 255], 1);
        __syncthreads();
        int c = sm0[t];
        int node = (blk << BUCK_BITS) + t;
        if (node < N) nd[node] = rsqrtf((float)(c + 1));
        sm1[t] = c;                          // pos
        __syncthreads();
        for (int off = 1; off < 256; off <<= 1) {
            int x = (t >= off) ? sm1[t - off] : 0;
            __syncthreads();
            sm1[t] += x;
            __syncthreads();
        }
        int start = e0 + sm1[t] - c - ebase;
        sm1[t] = start;
        if (node < N) rp[node] = start;
        __syncthreads();
        for (int e = e0 + t; e < e1; e += 256) {
            u32 w = a.binned[e];
            int i = (w >> 16) & 255;
            int r = atomicAdd(&sm2[i], 1);
            es[sm1[i] + r] = (int)(w & 0xFFFFu);
        }
    } else if (bid < a.ndst2) {
        // src bucket: count only -> norm_s
        int b2 = bid - ndst;
        int blk, offm, nblkm, N; float* ns;
        if (b2 < a.nbinsA) { blk = b2; offm = a.offAs; nblkm = a.nblkA; ns = a.nsA; N = a.NA; }
        else { blk = b2 - a.nbinsA; offm = a.offBs; nblkm = a.nblkB; ns = a.nsB; N = a.NB; }
        int e0 = a.ch[offm + blk * nblkm];
        int e1 = a.ch[offm + (blk + 1) * nblkm];
        sm0[t] = 0;
        __syncthreads();
        for (int e = e0 + t; e < e1; e += 256) atomicAdd(&sm0[a.binned[e] & 255], 1);
        __syncthreads();
        int node = (blk << BUCK_BITS) + t;
        if (node < N) ns[node] = rsqrtf((float)(sm0[t] + 1));
    }
}

// ======== MFMA GEMM (f16, merged A+B): Y = f16( (X*ns) @ W ), contiguous rows ========
__global__ __launch_bounds__(256) void gemmF(
    const float* __restrict__ X32A, const f16* __restrict__ X16A, const f16* __restrict__ WtA,
    const float* __restrict__ nsA, f16* __restrict__ YA, int NA, int DA, int nblkA,
    const float* __restrict__ X32B, const f16* __restrict__ X16B, const f16* __restrict__ WtB,
    const float* __restrict__ nsB, f16* __restrict__ YB, int NB, int DB, int xf16) {
    const float* X32; const f16* X16; const f16* Wt; const float* ns; f16* Y; int N, D, bid;
    if ((int)blockIdx.x < nblkA) {
        X32 = X32A; X16 = X16A; Wt = WtA; ns = nsA; Y = YA; N = NA; D = DA; bid = blockIdx.x;
    } else {
        X32 = X32B; X16 = X16B; Wt = WtB; ns = nsB; Y = YB; N = NB; D = DB; bid = blockIdx.x - nblkA;
    }
    __shared__ f16 Xs[64 * LDSTR];
    __shared__ f16 Ws[128 * LDSTR];
    int t = threadIdx.x;
    int wv = t >> 6, lane = t & 63;
    int m = lane & 15, q = lane >> 4;
    int rowbase = bid * 64;

    floatx4 acc[8];
#pragma unroll
    for (int c = 0; c < 8; c++) acc[c] = (floatx4)(0.f);

    for (int k0 = 0; k0 < D; k0 += BK) {
        __syncthreads();
        if (xf16) {   // stage pre-scaled f16 X: plain 16B copies
            int kq = (t & 7) * 8;
            int r0 = t >> 3;
#pragma unroll
            for (int i = 0; i < 2; i++) {
                int r = r0 + i * 32;
                int grow = rowbase + r;
                f16x8 v = (f16x8)(f16)0;
                if (grow < N) v = *(const f16x8*)(X16 + (size_t)grow * D + k0 + kq);
                *(f16x8*)&Xs[r * LDSTR + kq] = v;
            }
        } else {      // stage fp32 X: fold norm_s, convert to f16
            int kq = (t & 15) * 4;
#pragma unroll
            for (int i = 0; i < 4; i++) {
                int r = (t >> 4) + i * 16;
                int grow = rowbase + r;
                float4 v = make_float4(0.f, 0.f, 0.f, 0.f);
                float nv = 0.f;
                if (grow < N) {
                    v = *(const float4*)(X32 + (size_t)grow * D + k0 + kq);
                    nv = ns[grow];
                }
                f16x4 hv;
                hv[0] = (f16)(v.x * nv); hv[1] = (f16)(v.y * nv);
                hv[2] = (f16)(v.z * nv); hv[3] = (f16)(v.w * nv);
                *(f16x4*)&Xs[r * LDSTR + kq] = hv;
            }
        }
        {   // stage W chunk: 128 c x 64 k
            int ks = (t & 7) * 8;
            int rb = t >> 3;
#pragma unroll
            for (int i = 0; i < 4; i++) {
                int c = rb + i * 32;
                *(f16x8*)&Ws[c * LDSTR + ks] = *(const f16x8*)&Wt[(size_t)c * D + k0 + ks];
            }
        }
        __syncthreads();
#pragma unroll
        for (int ks = 0; ks < BK; ks += 32) {
            f16x8 a = *(const f16x8*)&Xs[(wv * 16 + m) * LDSTR + ks + q * 8];
#pragma unroll
            for (int c = 0; c < 8; c++) {
                f16x8 b = *(const f16x8*)&Ws[(c * 16 + m) * LDSTR + ks + q * 8];
                acc[c] = __builtin_amdgcn_mfma_f32_16x16x32_f16(a, b, acc[c], 0, 0, 0);
            }
        }
    }
    // D layout col=lane&15, row=(lane>>4)*4+reg ; contiguous f16 row store
#pragma unroll
    for (int c = 0; c < 8; c++)
#pragma unroll
        for (int r = 0; r < 4; r++) {
            int grow = rowbase + wv * 16 + q * 4 + r;
            if (grow < N) Y[(size_t)grow * H + c * 16 + m] = (f16)acc[c][r];
        }
}

// ======== aggregation v4: 1 node per 8-lane subgroup, 4 edges/round, index prefetch ========
__global__ __launch_bounds__(256) void aggC(
    const f16* __restrict__ YA, const int* __restrict__ rpA, const int* __restrict__ esA,
    const float* __restrict__ ndA, const float* __restrict__ nsA, const float* __restrict__ bA,
    float* __restrict__ oA, f16* __restrict__ hA, int nA32, int NA,
    const f16* __restrict__ YB, const int* __restrict__ rpB, const int* __restrict__ esB,
    const float* __restrict__ ndB, const float* __restrict__ nsB, const float* __restrict__ bB,
    float* __restrict__ oB, f16* __restrict__ hB, int NB, int layer0) {
    const f16* Y; const int *rp, *es; const float *nd, *ns, *bias; float* out; f16* hout;
    int N, blk;
    if ((int)blockIdx.x < nA32) {
        Y = YA; rp = rpA; es = esA; nd = ndA; ns = nsA; bias = bA; out = oA; hout = hA;
        N = NA; blk = blockIdx.x;
    } else {
        Y = YB; rp = rpB; es = esB; nd = ndB; ns = nsB; bias = bB; out = oB; hout = hB;
        N = NB; blk = blockIdx.x - nA32;
    }
    int t = threadIdx.x;
    int slot = t >> 3;
    int d = t & 7;
    int node = blk * 32 + slot;
    bool act = node < N;
    int nc = act ? node : (N - 1);
    int beg = rp[nc];
    int cnt = act ? (rp[nc + 1] - beg) : 0;
    int tot = cnt + 1;
    const f16* Yd = Y + (size_t)d * 16;
    float acc[16];
#pragma unroll
    for (int i = 0; i < 16; i++) acc[i] = 0.f;
    int i0 = (0 < cnt) ? es[beg]     : nc;
    int i1 = (1 < cnt) ? es[beg + 1] : nc;
    int i2 = (2 < cnt) ? es[beg + 2] : nc;
    int i3 = (3 < cnt) ? es[beg + 3] : nc;
    int j = 0;
    for (; j + 4 <= tot; j += 4) {
        f16x8 a0 = *(const f16x8*)(Yd + (size_t)i0 * H);
        f16x8 b0 = *(const f16x8*)(Yd + (size_t)i0 * H + 8);
        f16x8 a1 = *(const f16x8*)(Yd + (size_t)i1 * H);
        f16x8 b1 = *(const f16x8*)(Yd + (size_t)i1 * H + 8);
        f16x8 a2 = *(const f16x8*)(Yd + (size_t)i2 * H);
        f16x8 b2 = *(const f16x8*)(Yd + (size_t)i2 * H + 8);
        f16x8 a3 = *(const f16x8*)(Yd + (size_t)i3 * H);
        f16x8 b3 = *(const f16x8*)(Yd + (size_t)i3 * H + 8);
        int jn = j + 4;
        int n0 = (jn     < cnt) ? es[beg + jn]     : nc;
        int n1 = (jn + 1 < cnt) ? es[beg + jn + 1] : nc;
        int n2 = (jn + 2 < cnt) ? es[beg + jn + 2] : nc;
        int n3 = (jn + 3 < cnt) ? es[beg + jn + 3] : nc;
#pragma unroll
        for (int i = 0; i < 8; i++) {
            acc[i]     += ((float)a0[i] + (float)a1[i]) + ((float)a2[i] + (float)a3[i]);
            acc[i + 8] += ((float)b0[i] + (float)b1[i]) + ((float)b2[i] + (float)b3[i]);
        }
        i0 = n0; i1 = n1; i2 = n2; i3 = n3;
    }
    int rem = tot - j;
    if (rem > 0) {
        f16x8 a0 = *(const f16x8*)(Yd + (size_t)i0 * H);
        f16x8 b0 = *(const f16x8*)(Yd + (size_t)i0 * H + 8);
        if (rem > 1) {
            f16x8 a1 = *(const f16x8*)(Yd + (size_t)i1 * H);
            f16x8 b1 = *(const f16x8*)(Yd + (size_t)i1 * H + 8);
            if (rem > 2) {
                f16x8 a2 = *(const f16x8*)(Yd + (size_t)i2 * H);
                f16x8 b2 = *(const f16x8*)(Yd + (size_t)i2 * H + 8);
#pragma unroll
                for (int i = 0; i < 8; i++) {
                    acc[i]     += ((float)a0[i] + (float)a1[i]) + (float)a2[i];
                    acc[i + 8] += ((float)b0[i] + (float)b1[i]) + (float)b2[i];
                }
            } else {
#pragma unroll
                for (int i = 0; i < 8; i++) {
                    acc[i]     += (float)a0[i] + (float)a1[i];
                    acc[i + 8] += (float)b0[i] + (float)b1[i];
                }
            }
        } else {
#pragma unroll
            for (int i = 0; i < 8; i++) {
                acc[i]     += (float)a0[i];
                acc[i + 8] += (float)b0[i];
            }
        }
    }
    if (act) {
        float ndv = nd[node];
        float4 c0 = *(const float4*)(bias + d * 16);
        float4 c1 = *(const float4*)(bias + d * 16 + 4);
        float4 c2 = *(const float4*)(bias + d * 16 + 8);
        float4 c3 = *(const float4*)(bias + d * 16 + 12);
        float o_[16];
        o_[0]  = fmaf(acc[0],  ndv, c0.x); o_[1]  = fmaf(acc[1],  ndv, c0.y);
        o_[2]  = fmaf(acc[2],  ndv, c0.z); o_[3]  = fmaf(acc[3],  ndv, c0.w);
        o_[4]  = fmaf(acc[4],  ndv, c1.x); o_[5]  = fmaf(acc[5],  ndv, c1.y);
        o_[6]  = fmaf(acc[6],  ndv, c1.z); o_[7]  = fmaf(acc[7],  ndv, c1.w);
        o_[8]  = fmaf(acc[8],  ndv, c2.x); o_[9]  = fmaf(acc[9],  ndv, c2.y);
        o_[10] = fmaf(acc[10], ndv, c2.z); o_[11] = fmaf(acc[11], ndv, c2.w);
        o_[12] = fmaf(acc[12], ndv, c3.x); o_[13] = fmaf(acc[13], ndv, c3.y);
        o_[14] = fmaf(acc[14], ndv, c3.z); o_[15] = fmaf(acc[15], ndv, c3.w);
        if (layer0) {
            float nsv = ns[node];
            f16x8 h0, h1;
#pragma unroll
            for (int i = 0; i < 8; i++) {
                h0[i] = (f16)(fmaxf(o_[i], 0.f) * nsv);
                h1[i] = (f16)(fmaxf(o_[i + 8], 0.f) * nsv);
            }
            *(f16x8*)(hout + (size_t)node * H + d * 16) = h0;
            *(f16x8*)(hout + (size_t)node * H + d * 16 + 8) = h1;
        } else {
            float* op = out + (size_t)node * H + d * 16;
            *(float4*)op       = make_float4(o_[0],  o_[1],  o_[2],  o_[3]);
            *(float4*)(op + 4) = make_float4(o_[4],  o_[5],  o_[6],  o_[7]);
            *(float4*)(op + 8) = make_float4(o_[8],  o_[9],  o_[10], o_[11]);
            *(float4*)(op + 12)= make_float4(o_[12], o_[13], o_[14], o_[15]);
        }
    }
}

// ---------------- host ----------------

struct TypeBufs {
    int *rowptr, *esrc;
    float *norm_s, *norm_d;
    f16 *h, *y, *wt0, *wt1;
};

extern "C" void kernel_launch(void* const* d_in, const int* in_sizes, int n_in,
                              void* d_out, int out_size, void* d_ws, size_t ws_size,
                              hipStream_t stream) {
    (void)n_in; (void)out_size; (void)ws_size;
    const float* feat_a = (const float*)d_in[0];
    const float* feat_b = (const float*)d_in[1];
    const int* src_a = (const int*)d_in[2];
    const int* dst_a = (const int*)d_in[3];
    const int* src_b = (const int*)d_in[4];
    const int* dst_b = (const int*)d_in[5];
    const float* Wa0 = (const float*)d_in[6];
    const float* ba0 = (const float*)d_in[7];
    const float* Wa1 = (const float*)d_in[8];
    const float* ba1 = (const float*)d_in[9];
    const float* Wb0 = (const float*)d_in[10];
    const float* bb0 = (const float*)d_in[11];
    const float* Wb1 = (const float*)d_in[12];
    const float* bb1 = (const float*)d_in[13];

    const int DA = in_sizes[6] / H;   // 256
    const int DB = in_sizes[10] / H;  // 128
    const int NA = in_sizes[0] / DA;  // 50000
    const int NB = in_sizes[1] / DB;  // 30000
    const int EA = in_sizes[2];       // 600000
    const int EB = in_sizes[4];       // 300000

    const int nblkA = ceil_div(EA, EPB), nblkB = ceil_div(EB, EPB);
    const int nbinsA = ceil_div(NA, BUCK), nbinsB = ceil_div(NB, BUCK);
    const int LAd = nbinsA * nblkA, LBd = nbinsB * nblkB;
    const int offAd = 0;
    const int offBd = LAd;
    const int offAs = offBd + LBd;
    const int offBs = offAs + LAd;
    const int Lall = offBs + LBd;

    char* w = (char*)d_ws;
    auto carve = [&](size_t bytes) {
        void* p = (void*)w;
        w += (bytes + 255) & ~(size_t)255;
        return p;
    };
    int* ch = (int*)carve(((size_t)Lall + 1) * 4);
    int* bsum = (int*)carve(256 * 4);
    u32* binned = (u32*)carve((size_t)2 * (EA + EB) * 4);
    auto carve_type = [&](int N, int E, int D) {
        TypeBufs tb;
        tb.rowptr = (int*)carve(((size_t)N + 1) * 4);
        tb.esrc   = (int*)carve((size_t)E * 4);
        tb.norm_s = (float*)carve((size_t)N * 4);
        tb.norm_d = (float*)carve((size_t)N * 4);
        tb.h      = (f16*)carve((size_t)N * H * 2);
        tb.y      = (f16*)carve((size_t)N * H * 2);
        tb.wt0    = (f16*)carve((size_t)D * H * 2);
        tb.wt1    = (f16*)carve((size_t)H * H * 2);
        return tb;
    };
    TypeBufs A = carve_type(NA, EA, DA);
    TypeBufs B = carve_type(NB, EB, DB);

    float* out_a = (float*)d_out;
    float* out_b = out_a + (size_t)NA * H;

    const int gblkA = ceil_div(NA, 64), gblkB = ceil_div(NB, 64);
    const int nA32 = ceil_div(NA, 32), nB32 = ceil_div(NB, 32);
    const int wcBlocks = (DA + 3 * H) / 2;
    const int nScan = Lall + 1;
    const int sb1 = ceil_div(nScan, 1024);
    const int p1n = nblkA + nblkB;
    const int ndst2 = 2 * (nbinsA + nbinsB);

    // cooperative grid = max over all phase widths
    int nGrid = p1n + wcBlocks;
    if (ndst2 > nGrid) nGrid = ndst2;
    int s3b = ceil_div(nScan, 256);
    if (s3b > nGrid) nGrid = s3b;
    if (sb1 > nGrid) nGrid = sb1;

    PrepArgs pa;
    pa.sA = src_a; pa.dA = dst_a; pa.EA = EA; pa.nblkA = nblkA; pa.nbinsA = nbinsA;
    pa.sB = src_b; pa.dB = dst_b; pa.EB = EB; pa.nblkB = nblkB; pa.nbinsB = nbinsB;
    pa.ch = ch; pa.offAd = offAd; pa.offBd = offBd; pa.offAs = offAs; pa.offBs = offBs; pa.Lall = Lall;
    pa.Wa0 = Wa0; pa.ta0 = A.wt0; pa.Wa1 = Wa1; pa.ta1 = A.wt1;
    pa.Wb0 = Wb0; pa.tb0 = B.wt0; pa.Wb1 = Wb1; pa.tb1 = B.wt1; pa.DA = DA;
    pa.nScan = nScan; pa.sb1 = sb1; pa.bsum = bsum;
    pa.binned = binned;
    pa.rpA = A.rowptr; pa.ndA = A.norm_d; pa.esA = A.esrc; pa.NA = NA;
    pa.rpB = B.rowptr; pa.ndB = B.norm_d; pa.esB = B.esrc; pa.NB = NB;
    pa.nsA = A.norm_s; pa.nsB = B.norm_s;
    pa.p1n = p1n; pa.wcB = wcBlocks; pa.ndst2 = ndst2;

    void* kargs[] = { (void*)&pa };
    hipLaunchCooperativeKernel((const void*)prepK, dim3(nGrid), dim3(256), kargs, 0, stream);

    // ---- layer 0 ----
    gemmF<<<gblkA + gblkB, 256, 0, stream>>>(
        feat_a, (const f16*)nullptr, A.wt0, A.norm_s, A.y, NA, DA, gblkA,
        feat_b, (const f16*)nullptr, B.wt0, B.norm_s, B.y, NB, DB, 0);
    aggC<<<nA32 + nB32, 256, 0, stream>>>(
        A.y, A.rowptr, A.esrc, A.norm_d, A.norm_s, ba0, out_a, A.h, nA32, NA,
        B.y, B.rowptr, B.esrc, B.norm_d, B.norm_s, bb0, out_b, B.h, NB, 1);
    // ---- layer 1 ----
    gemmF<<<gblkA + gblkB, 256, 0, stream>>>(
        (const float*)nullptr, A.h, A.wt1, A.norm_s, A.y, NA, H, gblkA,
        (const float*)nullptr, B.h, B.wt1, B.norm_s, B.y, NB, H, 1);
    aggC<<<nA32 + nB32, 256, 0, stream>>>(
        A.y, A.rowptr, A.esrc, A.norm_d, A.norm_s, ba1, out_a, A.h, nA32, NA,
        B.y, B.rowptr, B.esrc, B.norm_d, B.norm_s, bb1, out_b, B.h, NB, 0);
}

// Round 9
// 268.711 us; speedup vs baseline: 2.4533x; 2.4533x over previous
//
#include <hip/hip_runtime.h>
#include <hip/hip_bf16.h>

#define H 128
#define BK 64
#define LDSTR 72   // LDS row stride (f16 elems): 144B, 16B-aligned rows

#define EPB 4096        // edges per block, bucket passes
#define BUCK_BITS 8
#define BUCK 256        // nodes per bucket

typedef _Float16 f16;
typedef unsigned int u32;
typedef __attribute__((ext_vector_type(8))) _Float16 f16x8;
typedef __attribute__((ext_vector_type(4))) _Float16 f16x4;
typedef __attribute__((ext_vector_type(4))) float floatx4;

static inline __host__ int ceil_div(int a, int b) { return (a + b - 1) / b; }

// ======== P1: per-block 256-bin histograms of dst>>8 AND src>>8 | weight transpose ========
__global__ __launch_bounds__(256) void p1K(
    const int* __restrict__ sA, const int* __restrict__ dA, int EA, int nblkA, int nbinsA,
    const int* __restrict__ sB, const int* __restrict__ dB, int EB, int nblkB, int nbinsB,
    int* __restrict__ ch, int offAd, int offBd, int offAs, int offBs, int Lall,
    const float* __restrict__ Wa0, f16* ta0, const float* __restrict__ Wa1, f16* ta1,
    const float* __restrict__ Wb0, f16* tb0, const float* __restrict__ Wb1, f16* tb1, int DA) {
    __shared__ int bd[BUCK], bs[BUCK];
    int bid = blockIdx.x, t = threadIdx.x;
    int p1n = nblkA + nblkB;
    if (bid < p1n) {
        const int *src, *dst; int E, nblk, nbins, blk, od, os;
        if (bid < nblkA) { src = sA; dst = dA; E = EA; nblk = nblkA; nbins = nbinsA; blk = bid; od = offAd; os = offAs; }
        else { src = sB; dst = dB; E = EB; nblk = nblkB; nbins = nbinsB; blk = bid - nblkA; od = offBd; os = offBs; }
        bd[t] = 0; bs[t] = 0;
        __syncthreads();
        int e0 = blk * EPB, e1 = min(E, e0 + EPB);
        for (int e = e0 + t; e < e1; e += 256) {
            atomicAdd(&bd[dst[e] >> BUCK_BITS], 1);
            atomicAdd(&bs[src[e] >> BUCK_BITS], 1);
        }
        __syncthreads();
        for (int b = t; b < nbins; b += 256) {
            ch[od + b * nblk + blk] = bd[b];
            ch[os + b * nblk + blk] = bs[b];
        }
        if (bid == 0 && t == 0) ch[Lall] = 0;   // sentinel -> scanned value = grand total
    } else {
        int b2 = bid - p1n;                      // weight transpose: 2 k-rows per block
        int k2 = b2 * 2 + (t >> 7);
        const float* W; f16* T; int D, k;
        if (k2 < DA) { W = Wa0; T = ta0; D = DA; k = k2; }
        else if (k2 < DA + H) { W = Wa1; T = ta1; D = H; k = k2 - DA; }
        else if (k2 < DA + 2 * H) { W = Wb0; T = tb0; D = H; k = k2 - DA - H; }
        else { W = Wb1; T = tb1; D = H; k = k2 - DA - 2 * H; }
        int c = t & 127;
        T[(size_t)c * D + k] = (f16)W[(size_t)k * H + c];
    }
}

// ======== scan1: per-1024-chunk exclusive scan, chunk totals -> bsum ========
__global__ __launch_bounds__(256) void scan1K(int* __restrict__ ch, int n, int* __restrict__ bsum) {
    __shared__ int sh[256];
    int t = threadIdx.x;
    int base = blockIdx.x * 1024 + t * 4;
    int v[4];
#pragma unroll
    for (int i = 0; i < 4; i++) v[i] = (base + i < n) ? ch[base + i] : 0;
    int s = v[0] + v[1] + v[2] + v[3];
    sh[t] = s;
    __syncthreads();
    for (int off = 1; off < 256; off <<= 1) {
        int x = (t >= off) ? sh[t - off] : 0;
        __syncthreads();
        sh[t] += x;
        __syncthreads();
    }
    int run = sh[t] - s;
#pragma unroll
    for (int i = 0; i < 4; i++) {
        if (base + i < n) ch[base + i] = run;
        run += v[i];
    }
    if (t == 255) bsum[blockIdx.x] = sh[255];
}

// ======== scan23: merged scan2K+scan3K. Each block (256 ch entries, fully inside one
// 1024-chunk) redundantly scans bsum in LDS and adds the exclusive chunk offset. ========
__global__ __launch_bounds__(256) void scan23K(int* __restrict__ ch, const int* __restrict__ bsum,
                                               int nb, int n) {
    __shared__ int sh[256];
    int t = threadIdx.x;
    int v = (t < nb) ? bsum[t] : 0;
    sh[t] = v;
    __syncthreads();
    for (int off = 1; off < 256; off <<= 1) {
        int x = (t >= off) ? sh[t - off] : 0;
        __syncthreads();
        sh[t] += x;
        __syncthreads();
    }
    int k = blockIdx.x >> 2;               // chunk index (4 blocks per 1024-chunk)
    int add = (k == 0) ? 0 : sh[k - 1];    // exclusive prefix of chunk totals
    int i = blockIdx.x * 256 + t;
    if (i < n) ch[i] += add;
}

// ======== P3: scatter edges into bucket-ordered array, dst-keyed AND src-keyed ========
__global__ __launch_bounds__(256) void p3K(
    const int* __restrict__ sA, const int* __restrict__ dA, int EA, int nblkA, int nbinsA,
    const int* __restrict__ sB, const int* __restrict__ dB, int EB, int nblkB, int nbinsB,
    const int* __restrict__ ch, int offAd, int offBd, int offAs, int offBs,
    u32* __restrict__ binned) {
    __shared__ int cd[BUCK], cs[BUCK], ofd[BUCK], ofs[BUCK];
    const int *src, *dst; int E, nblk, nbins, blk, od, os;
    if ((int)blockIdx.x < nblkA) {
        src = sA; dst = dA; E = EA; nblk = nblkA; nbins = nbinsA; blk = blockIdx.x; od = offAd; os = offAs;
    } else {
        src = sB; dst = dB; E = EB; nblk = nblkB; nbins = nbinsB; blk = blockIdx.x - nblkA; od = offBd; os = offBs;
    }
    int t = threadIdx.x;
    cd[t] = 0; cs[t] = 0;
    if (t < nbins) {
        ofd[t] = ch[od + t * nblk + blk];
        ofs[t] = ch[os + t * nblk + blk];
    }
    __syncthreads();
    int e0 = blk * EPB, e1 = min(E, e0 + EPB);
    for (int e = e0 + t; e < e1; e += 256) {
        int d = dst[e], s = src[e];
        int b = d >> BUCK_BITS;
        int r = atomicAdd(&cd[b], 1);
        binned[ofd[b] + r] = (u32)s | ((u32)(d & (BUCK - 1)) << 16);
        int b2 = s >> BUCK_BITS;
        int r2 = atomicAdd(&cs[b2], 1);
        binned[ofs[b2] + r2] = (u32)(s & (BUCK - 1));
    }
}

// ======== P4: per-bucket fine pass. dst-buckets: norm_d+rowptr+esrc; src-buckets: norm_s ========
__global__ __launch_bounds__(256) void p4K(
    const u32* __restrict__ binned, const int* __restrict__ ch,
    int nbinsA, int nblkA, int offAd, int offAs,
    int nbinsB, int nblkB, int offBd, int offBs,
    int* __restrict__ rpA, float* __restrict__ ndA, int* __restrict__ esA, int NA, int EA,
    int* __restrict__ rpB, float* __restrict__ ndB, int* __restrict__ esB, int NB, int EB,
    float* __restrict__ nsA, float* __restrict__ nsB) {
    __shared__ int cnt[BUCK], pos[BUCK], fill[BUCK];
    int bid = blockIdx.x, t = threadIdx.x;
    int ndst = nbinsA + nbinsB;
    if (bid == 0 && t == 0) { rpA[NA] = EA; rpB[NB] = EB; }
    if (bid < ndst) {
        // ---- dst bucket: full CSR ----
        int blk, offm, nblkm, N, ebase; int* rp; float* nd; int* es;
        if (bid < nbinsA) { blk = bid; offm = offAd; nblkm = nblkA; rp = rpA; nd = ndA; es = esA; N = NA; ebase = 0; }
        else { blk = bid - nbinsA; offm = offBd; nblkm = nblkB; rp = rpB; nd = ndB; es = esB; N = NB; ebase = EA; }
        int e0 = ch[offm + blk * nblkm];
        int e1 = ch[offm + (blk + 1) * nblkm];   // next bucket start (or next matrix start)
        cnt[t] = 0; fill[t] = 0;
        __syncthreads();
        for (int e = e0 + t; e < e1; e += 256) atomicAdd(&cnt[(binned[e] >> 16) & 255], 1);
        __syncthreads();
        int c = cnt[t];
        int node = (blk << BUCK_BITS) + t;
        if (node < N) nd[node] = rsqrtf((float)(c + 1));
        pos[t] = c;
        __syncthreads();
        for (int off = 1; off < 256; off <<= 1) {
            int x = (t >= off) ? pos[t - off] : 0;
            __syncthreads();
            pos[t] += x;
            __syncthreads();
        }
        int start = e0 + pos[t] - c - ebase;     // within-type CSR start
        pos[t] = start;
        if (node < N) rp[node] = start;
        __syncthreads();
        for (int e = e0 + t; e < e1; e += 256) {
            u32 w = binned[e];
            int i = (w >> 16) & 255;
            int r = atomicAdd(&fill[i], 1);
            es[pos[i] + r] = (int)(w & 0xFFFFu);
        }
    } else {
        // ---- src bucket: count only -> norm_s ----
        int b2 = bid - ndst;
        int blk, offm, nblkm, N; float* ns;
        if (b2 < nbinsA) { blk = b2; offm = offAs; nblkm = nblkA; ns = nsA; N = NA; }
        else { blk = b2 - nbinsA; offm = offBs; nblkm = nblkB; ns = nsB; N = NB; }
        int e0 = ch[offm + blk * nblkm];
        int e1 = ch[offm + (blk + 1) * nblkm];
        cnt[t] = 0;
        __syncthreads();
        for (int e = e0 + t; e < e1; e += 256) atomicAdd(&cnt[binned[e] & 255], 1);
        __syncthreads();
        int node = (blk << BUCK_BITS) + t;
        if (node < N) ns[node] = rsqrtf((float)(cnt[t] + 1));
    }
}

// ======== MFMA GEMM (f16, merged A+B): Y = f16( (X*ns) @ W ), contiguous rows ========
__global__ __launch_bounds__(256) void gemmF(
    const float* __restrict__ X32A, const f16* __restrict__ X16A, const f16* __restrict__ WtA,
    const float* __restrict__ nsA, f16* __restrict__ YA, int NA, int DA, int nblkA,
    const float* __restrict__ X32B, const f16* __restrict__ X16B, const f16* __restrict__ WtB,
    const float* __restrict__ nsB, f16* __restrict__ YB, int NB, int DB, int xf16) {
    const float* X32; const f16* X16; const f16* Wt; const float* ns; f16* Y; int N, D, bid;
    if ((int)blockIdx.x < nblkA) {
        X32 = X32A; X16 = X16A; Wt = WtA; ns = nsA; Y = YA; N = NA; D = DA; bid = blockIdx.x;
    } else {
        X32 = X32B; X16 = X16B; Wt = WtB; ns = nsB; Y = YB; N = NB; D = DB; bid = blockIdx.x - nblkA;
    }
    __shared__ f16 Xs[64 * LDSTR];
    __shared__ f16 Ws[128 * LDSTR];
    int t = threadIdx.x;
    int wv = t >> 6, lane = t & 63;
    int m = lane & 15, q = lane >> 4;
    int rowbase = bid * 64;

    floatx4 acc[8];
#pragma unroll
    for (int c = 0; c < 8; c++) acc[c] = (floatx4)(0.f);

    for (int k0 = 0; k0 < D; k0 += BK) {
        __syncthreads();
        if (xf16) {   // stage pre-scaled f16 X: plain 16B copies
            int kq = (t & 7) * 8;
            int r0 = t >> 3;
#pragma unroll
            for (int i = 0; i < 2; i++) {
                int r = r0 + i * 32;
                int grow = rowbase + r;
                f16x8 v = (f16x8)(f16)0;
                if (grow < N) v = *(const f16x8*)(X16 + (size_t)grow * D + k0 + kq);
                *(f16x8*)&Xs[r * LDSTR + kq] = v;
            }
        } else {      // stage fp32 X: fold norm_s, convert to f16
            int kq = (t & 15) * 4;
#pragma unroll
            for (int i = 0; i < 4; i++) {
                int r = (t >> 4) + i * 16;
                int grow = rowbase + r;
                float4 v = make_float4(0.f, 0.f, 0.f, 0.f);
                float nv = 0.f;
                if (grow < N) {
                    v = *(const float4*)(X32 + (size_t)grow * D + k0 + kq);
                    nv = ns[grow];
                }
                f16x4 hv;
                hv[0] = (f16)(v.x * nv); hv[1] = (f16)(v.y * nv);
                hv[2] = (f16)(v.z * nv); hv[3] = (f16)(v.w * nv);
                *(f16x4*)&Xs[r * LDSTR + kq] = hv;
            }
        }
        {   // stage W chunk: 128 c x 64 k
            int ks = (t & 7) * 8;
            int rb = t >> 3;
#pragma unroll
            for (int i = 0; i < 4; i++) {
                int c = rb + i * 32;
                *(f16x8*)&Ws[c * LDSTR + ks] = *(const f16x8*)&Wt[(size_t)c * D + k0 + ks];
            }
        }
        __syncthreads();
#pragma unroll
        for (int ks = 0; ks < BK; ks += 32) {
            f16x8 a = *(const f16x8*)&Xs[(wv * 16 + m) * LDSTR + ks + q * 8];
#pragma unroll
            for (int c = 0; c < 8; c++) {
                f16x8 b = *(const f16x8*)&Ws[(c * 16 + m) * LDSTR + ks + q * 8];
                acc[c] = __builtin_amdgcn_mfma_f32_16x16x32_f16(a, b, acc[c], 0, 0, 0);
            }
        }
    }
    // D layout col=lane&15, row=(lane>>4)*4+reg ; contiguous f16 row store
#pragma unroll
    for (int c = 0; c < 8; c++)
#pragma unroll
        for (int r = 0; r < 4; r++) {
            int grow = rowbase + wv * 16 + q * 4 + r;
            if (grow < N) Y[(size_t)grow * H + c * 16 + m] = (f16)acc[c][r];
        }
}

// ======== aggregation v4: 1 node per 8-lane subgroup, 4 edges/round, index prefetch ========
__global__ __launch_bounds__(256) void aggC(
    const f16* __restrict__ YA, const int* __restrict__ rpA, const int* __restrict__ esA,
    const float* __restrict__ ndA, const float* __restrict__ nsA, const float* __restrict__ bA,
    float* __restrict__ oA, f16* __restrict__ hA, int nA32, int NA,
    const f16* __restrict__ YB, const int* __restrict__ rpB, const int* __restrict__ esB,
    const float* __restrict__ ndB, const float* __restrict__ nsB, const float* __restrict__ bB,
    float* __restrict__ oB, f16* __restrict__ hB, int NB, int layer0) {
    const f16* Y; const int *rp, *es; const float *nd, *ns, *bias; float* out; f16* hout;
    int N, blk;
    if ((int)blockIdx.x < nA32) {
        Y = YA; rp = rpA; es = esA; nd = ndA; ns = nsA; bias = bA; out = oA; hout = hA;
        N = NA; blk = blockIdx.x;
    } else {
        Y = YB; rp = rpB; es = esB; nd = ndB; ns = nsB; bias = bB; out = oB; hout = hB;
        N = NB; blk = blockIdx.x - nA32;
    }
    int t = threadIdx.x;
    int slot = t >> 3;
    int d = t & 7;
    int node = blk * 32 + slot;
    bool act = node < N;
    int nc = act ? node : (N - 1);
    int beg = rp[nc];
    int cnt = act ? (rp[nc + 1] - beg) : 0;
    int tot = cnt + 1;
    const f16* Yd = Y + (size_t)d * 16;
    float acc[16];
#pragma unroll
    for (int i = 0; i < 16; i++) acc[i] = 0.f;
    int i0 = (0 < cnt) ? es[beg]     : nc;
    int i1 = (1 < cnt) ? es[beg + 1] : nc;
    int i2 = (2 < cnt) ? es[beg + 2] : nc;
    int i3 = (3 < cnt) ? es[beg + 3] : nc;
    int j = 0;
    for (; j + 4 <= tot; j += 4) {
        f16x8 a0 = *(const f16x8*)(Yd + (size_t)i0 * H);
        f16x8 b0 = *(const f16x8*)(Yd + (size_t)i0 * H + 8);
        f16x8 a1 = *(const f16x8*)(Yd + (size_t)i1 * H);
        f16x8 b1 = *(const f16x8*)(Yd + (size_t)i1 * H + 8);
        f16x8 a2 = *(const f16x8*)(Yd + (size_t)i2 * H);
        f16x8 b2 = *(const f16x8*)(Yd + (size_t)i2 * H + 8);
        f16x8 a3 = *(const f16x8*)(Yd + (size_t)i3 * H);
        f16x8 b3 = *(const f16x8*)(Yd + (size_t)i3 * H + 8);
        int jn = j + 4;
        int n0 = (jn     < cnt) ? es[beg + jn]     : nc;
        int n1 = (jn + 1 < cnt) ? es[beg + jn + 1] : nc;
        int n2 = (jn + 2 < cnt) ? es[beg + jn + 2] : nc;
        int n3 = (jn + 3 < cnt) ? es[beg + jn + 3] : nc;
#pragma unroll
        for (int i = 0; i < 8; i++) {
            acc[i]     += ((float)a0[i] + (float)a1[i]) + ((float)a2[i] + (float)a3[i]);
            acc[i + 8] += ((float)b0[i] + (float)b1[i]) + ((float)b2[i] + (float)b3[i]);
        }
        i0 = n0; i1 = n1; i2 = n2; i3 = n3;
    }
    int rem = tot - j;
    if (rem > 0) {
        f16x8 a0 = *(const f16x8*)(Yd + (size_t)i0 * H);
        f16x8 b0 = *(const f16x8*)(Yd + (size_t)i0 * H + 8);
        if (rem > 1) {
            f16x8 a1 = *(const f16x8*)(Yd + (size_t)i1 * H);
            f16x8 b1 = *(const f16x8*)(Yd + (size_t)i1 * H + 8);
            if (rem > 2) {
                f16x8 a2 = *(const f16x8*)(Yd + (size_t)i2 * H);
                f16x8 b2 = *(const f16x8*)(Yd + (size_t)i2 * H + 8);
#pragma unroll
                for (int i = 0; i < 8; i++) {
                    acc[i]     += ((float)a0[i] + (float)a1[i]) + (float)a2[i];
                    acc[i + 8] += ((float)b0[i] + (float)b1[i]) + (float)b2[i];
                }
            } else {
#pragma unroll
                for (int i = 0; i < 8; i++) {
                    acc[i]     += (float)a0[i] + (float)a1[i];
                    acc[i + 8] += (float)b0[i] + (float)b1[i];
                }
            }
        } else {
#pragma unroll
            for (int i = 0; i < 8; i++) {
                acc[i]     += (float)a0[i];
                acc[i + 8] += (float)b0[i];
            }
        }
    }
    if (act) {
        float ndv = nd[node];
        float4 c0 = *(const float4*)(bias + d * 16);
        float4 c1 = *(const float4*)(bias + d * 16 + 4);
        float4 c2 = *(const float4*)(bias + d * 16 + 8);
        float4 c3 = *(const float4*)(bias + d * 16 + 12);
        float o_[16];
        o_[0]  = fmaf(acc[0],  ndv, c0.x); o_[1]  = fmaf(acc[1],  ndv, c0.y);
        o_[2]  = fmaf(acc[2],  ndv, c0.z); o_[3]  = fmaf(acc[3],  ndv, c0.w);
        o_[4]  = fmaf(acc[4],  ndv, c1.x); o_[5]  = fmaf(acc[5],  ndv, c1.y);
        o_[6]  = fmaf(acc[6],  ndv, c1.z); o_[7]  = fmaf(acc[7],  ndv, c1.w);
        o_[8]  = fmaf(acc[8],  ndv, c2.x); o_[9]  = fmaf(acc[9],  ndv, c2.y);
        o_[10] = fmaf(acc[10], ndv, c2.z); o_[11] = fmaf(acc[11], ndv, c2.w);
        o_[12] = fmaf(acc[12], ndv, c3.x); o_[13] = fmaf(acc[13], ndv, c3.y);
        o_[14] = fmaf(acc[14], ndv, c3.z); o_[15] = fmaf(acc[15], ndv, c3.w);
        if (layer0) {
            float nsv = ns[node];
            f16x8 h0, h1;
#pragma unroll
            for (int i = 0; i < 8; i++) {
                h0[i] = (f16)(fmaxf(o_[i], 0.f) * nsv);
                h1[i] = (f16)(fmaxf(o_[i + 8], 0.f) * nsv);
            }
            *(f16x8*)(hout + (size_t)node * H + d * 16) = h0;
            *(f16x8*)(hout + (size_t)node * H + d * 16 + 8) = h1;
        } else {
            float* op = out + (size_t)node * H + d * 16;
            *(float4*)op       = make_float4(o_[0],  o_[1],  o_[2],  o_[3]);
            *(float4*)(op + 4) = make_float4(o_[4],  o_[5],  o_[6],  o_[7]);
            *(float4*)(op + 8) = make_float4(o_[8],  o_[9],  o_[10], o_[11]);
            *(float4*)(op + 12)= make_float4(o_[12], o_[13], o_[14], o_[15]);
        }
    }
}

// ---------------- host ----------------

struct TypeBufs {
    int *rowptr, *esrc;
    float *norm_s, *norm_d;
    f16 *h, *y, *wt0, *wt1;
};

extern "C" void kernel_launch(void* const* d_in, const int* in_sizes, int n_in,
                              void* d_out, int out_size, void* d_ws, size_t ws_size,
                              hipStream_t stream) {
    (void)n_in; (void)out_size; (void)ws_size;
    const float* feat_a = (const float*)d_in[0];
    const float* feat_b = (const float*)d_in[1];
    const int* src_a = (const int*)d_in[2];
    const int* dst_a = (const int*)d_in[3];
    const int* src_b = (const int*)d_in[4];
    const int* dst_b = (const int*)d_in[5];
    const float* Wa0 = (const float*)d_in[6];
    const float* ba0 = (const float*)d_in[7];
    const float* Wa1 = (const float*)d_in[8];
    const float* ba1 = (const float*)d_in[9];
    const float* Wb0 = (const float*)d_in[10];
    const float* bb0 = (const float*)d_in[11];
    const float* Wb1 = (const float*)d_in[12];
    const float* bb1 = (const float*)d_in[13];

    const int DA = in_sizes[6] / H;   // 256
    const int DB = in_sizes[10] / H;  // 128
    const int NA = in_sizes[0] / DA;  // 50000
    const int NB = in_sizes[1] / DB;  // 30000
    const int EA = in_sizes[2];       // 600000
    const int EB = in_sizes[4];       // 300000

    const int nblkA = ceil_div(EA, EPB), nblkB = ceil_div(EB, EPB);
    const int nbinsA = ceil_div(NA, BUCK), nbinsB = ceil_div(NB, BUCK);
    const int LAd = nbinsA * nblkA, LBd = nbinsB * nblkB;
    const int offAd = 0;
    const int offBd = LAd;
    const int offAs = offBd + LBd;
    const int offBs = offAs + LAd;
    const int Lall = offBs + LBd;

    char* w = (char*)d_ws;
    auto carve = [&](size_t bytes) {
        void* p = (void*)w;
        w += (bytes + 255) & ~(size_t)255;
        return p;
    };
    int* ch = (int*)carve(((size_t)Lall + 1) * 4);
    int* bsum = (int*)carve(256 * 4);
    u32* binned = (u32*)carve((size_t)2 * (EA + EB) * 4);
    auto carve_type = [&](int N, int E, int D) {
        TypeBufs tb;
        tb.rowptr = (int*)carve(((size_t)N + 1) * 4);
        tb.esrc   = (int*)carve((size_t)E * 4);
        tb.norm_s = (float*)carve((size_t)N * 4);
        tb.norm_d = (float*)carve((size_t)N * 4);
        tb.h      = (f16*)carve((size_t)N * H * 2);
        tb.y      = (f16*)carve((size_t)N * H * 2);
        tb.wt0    = (f16*)carve((size_t)D * H * 2);
        tb.wt1    = (f16*)carve((size_t)H * H * 2);
        return tb;
    };
    TypeBufs A = carve_type(NA, EA, DA);
    TypeBufs B = carve_type(NB, EB, DB);

    float* out_a = (float*)d_out;
    float* out_b = out_a + (size_t)NA * H;

    const int gblkA = ceil_div(NA, 64), gblkB = ceil_div(NB, 64);
    const int nA32 = ceil_div(NA, 32), nB32 = ceil_div(NB, 32);
    const int wcBlocks = (DA + 3 * H) / 2;
    const int nScan = Lall + 1;
    const int sb1 = ceil_div(nScan, 1024);

    // ---- prep: 5 launches (scan2+scan3 merged), all wide-parallel ----
    p1K<<<nblkA + nblkB + wcBlocks, 256, 0, stream>>>(
        src_a, dst_a, EA, nblkA, nbinsA, src_b, dst_b, EB, nblkB, nbinsB,
        ch, offAd, offBd, offAs, offBs, Lall,
        Wa0, A.wt0, Wa1, A.wt1, Wb0, B.wt0, Wb1, B.wt1, DA);
    scan1K<<<sb1, 256, 0, stream>>>(ch, nScan, bsum);
    scan23K<<<ceil_div(nScan, 256), 256, 0, stream>>>(ch, bsum, sb1, nScan);
    p3K<<<nblkA + nblkB, 256, 0, stream>>>(
        src_a, dst_a, EA, nblkA, nbinsA, src_b, dst_b, EB, nblkB, nbinsB,
        ch, offAd, offBd, offAs, offBs, binned);
    p4K<<<2 * (nbinsA + nbinsB), 256, 0, stream>>>(
        binned, ch, nbinsA, nblkA, offAd, offAs, nbinsB, nblkB, offBd, offBs,
        A.rowptr, A.norm_d, A.esrc, NA, EA,
        B.rowptr, B.norm_d, B.esrc, NB, EB,
        A.norm_s, B.norm_s);
    // ---- layer 0 ----
    gemmF<<<gblkA + gblkB, 256, 0, stream>>>(
        feat_a, (const f16*)nullptr, A.wt0, A.norm_s, A.y, NA, DA, gblkA,
        feat_b, (const f16*)nullptr, B.wt0, B.norm_s, B.y, NB, DB, 0);
    aggC<<<nA32 + nB32, 256, 0, stream>>>(
        A.y, A.rowptr, A.esrc, A.norm_d, A.norm_s, ba0, out_a, A.h, nA32, NA,
        B.y, B.rowptr, B.esrc, B.norm_d, B.norm_s, bb0, out_b, B.h, NB, 1);
    // ---- layer 1 ----
    gemmF<<<gblkA + gblkB, 256, 0, stream>>>(
        (const float*)nullptr, A.h, A.wt1, A.norm_s, A.y, NA, H, gblkA,
        (const float*)nullptr, B.h, B.wt1, B.norm_s, B.y, NB, H, 1);
    aggC<<<nA32 + nB32, 256, 0, stream>>>(
        A.y, A.rowptr, A.esrc, A.norm_d, A.norm_s, ba1, out_a, A.h, nA32, NA,
        B.y, B.rowptr, B.esrc, B.norm_d, B.norm_s, bb1, out_b, B.h, NB, 0);
}

// Round 12
// 264.777 us; speedup vs baseline: 2.4897x; 1.0149x over previous
//
#include <hip/hip_runtime.h>
#include <hip/hip_bf16.h>

#define H 128
#define BK 64
#define LDSTR 72   // LDS row stride (f16 elems): 144B, 16B-aligned rows

#define EPB 2048        // edges per block, bucket passes (halved: prep occupancy)
#define BUCK_BITS 8
#define BUCK 256        // nodes per bucket

typedef _Float16 f16;
typedef unsigned int u32;
typedef __attribute__((ext_vector_type(8))) _Float16 f16x8;
typedef __attribute__((ext_vector_type(4))) _Float16 f16x4;
typedef __attribute__((ext_vector_type(4))) float floatx4;

static inline __host__ int ceil_div(int a, int b) { return (a + b - 1) / b; }

// ======== P1: per-block 256-bin histograms of dst>>8 AND src>>8 | weight transpose ========
__global__ __launch_bounds__(256) void p1K(
    const int* __restrict__ sA, const int* __restrict__ dA, int EA, int nblkA, int nbinsA,
    const int* __restrict__ sB, const int* __restrict__ dB, int EB, int nblkB, int nbinsB,
    int* __restrict__ ch, int offAd, int offBd, int offAs, int offBs, int Lall,
    const float* __restrict__ Wa0, f16* ta0, const float* __restrict__ Wa1, f16* ta1,
    const float* __restrict__ Wb0, f16* tb0, const float* __restrict__ Wb1, f16* tb1, int DA) {
    __shared__ int bd[BUCK], bs[BUCK];
    int bid = blockIdx.x, t = threadIdx.x;
    int p1n = nblkA + nblkB;
    if (bid < p1n) {
        const int *src, *dst; int E, nblk, nbins, blk, od, os;
        if (bid < nblkA) { src = sA; dst = dA; E = EA; nblk = nblkA; nbins = nbinsA; blk = bid; od = offAd; os = offAs; }
        else { src = sB; dst = dB; E = EB; nblk = nblkB; nbins = nbinsB; blk = bid - nblkA; od = offBd; os = offBs; }
        bd[t] = 0; bs[t] = 0;
        __syncthreads();
        int e0 = blk * EPB, e1 = min(E, e0 + EPB);
        for (int e = e0 + t; e < e1; e += 256) {
            atomicAdd(&bd[dst[e] >> BUCK_BITS], 1);
            atomicAdd(&bs[src[e] >> BUCK_BITS], 1);
        }
        __syncthreads();
        for (int b = t; b < nbins; b += 256) {
            ch[od + b * nblk + blk] = bd[b];
            ch[os + b * nblk + blk] = bs[b];
        }
        if (bid == 0 && t == 0) ch[Lall] = 0;   // sentinel -> scanned value = grand total
    } else {
        int b2 = bid - p1n;                      // weight transpose: 2 k-rows per block
        int k2 = b2 * 2 + (t >> 7);
        const float* W; f16* T; int D, k;
        if (k2 < DA) { W = Wa0; T = ta0; D = DA; k = k2; }
        else if (k2 < DA + H) { W = Wa1; T = ta1; D = H; k = k2 - DA; }
        else if (k2 < DA + 2 * H) { W = Wb0; T = tb0; D = H; k = k2 - DA - H; }
        else { W = Wb1; T = tb1; D = H; k = k2 - DA - 2 * H; }
        int c = t & 127;
        T[(size_t)c * D + k] = (f16)W[(size_t)k * H + c];
    }
}

// ======== scan1: per-1024-chunk exclusive scan, chunk totals -> bsum ========
__global__ __launch_bounds__(256) void scan1K(int* __restrict__ ch, int n, int* __restrict__ bsum) {
    __shared__ int sh[256];
    int t = threadIdx.x;
    int base = blockIdx.x * 1024 + t * 4;
    int v[4];
#pragma unroll
    for (int i = 0; i < 4; i++) v[i] = (base + i < n) ? ch[base + i] : 0;
    int s = v[0] + v[1] + v[2] + v[3];
    sh[t] = s;
    __syncthreads();
    for (int off = 1; off < 256; off <<= 1) {
        int x = (t >= off) ? sh[t - off] : 0;
        __syncthreads();
        sh[t] += x;
        __syncthreads();
    }
    int run = sh[t] - s;
#pragma unroll
    for (int i = 0; i < 4; i++) {
        if (base + i < n) ch[base + i] = run;
        run += v[i];
    }
    if (t == 255) bsum[blockIdx.x] = sh[255];
}

// ======== scan23: merged scan2K+scan3K. Each block (256 ch entries, fully inside one
// 1024-chunk) redundantly scans bsum in LDS and adds the exclusive chunk offset. ========
__global__ __launch_bounds__(256) void scan23K(int* __restrict__ ch, const int* __restrict__ bsum,
                                               int nb, int n) {
    __shared__ int sh[256];
    int t = threadIdx.x;
    int v = (t < nb) ? bsum[t] : 0;
    sh[t] = v;
    __syncthreads();
    for (int off = 1; off < 256; off <<= 1) {
        int x = (t >= off) ? sh[t - off] : 0;
        __syncthreads();
        sh[t] += x;
        __syncthreads();
    }
    int k = blockIdx.x >> 2;               // chunk index (4 blocks per 1024-chunk)
    int add = (k == 0) ? 0 : sh[k - 1];    // exclusive prefix of chunk totals
    int i = blockIdx.x * 256 + t;
    if (i < n) ch[i] += add;
}

// ======== P3: scatter edges into bucket-ordered array, dst-keyed AND src-keyed ========
__global__ __launch_bounds__(256) void p3K(
    const int* __restrict__ sA, const int* __restrict__ dA, int EA, int nblkA, int nbinsA,
    const int* __restrict__ sB, const int* __restrict__ dB, int EB, int nblkB, int nbinsB,
    const int* __restrict__ ch, int offAd, int offBd, int offAs, int offBs,
    u32* __restrict__ binned) {
    __shared__ int cd[BUCK], cs[BUCK], ofd[BUCK], ofs[BUCK];
    const int *src, *dst; int E, nblk, nbins, blk, od, os;
    if ((int)blockIdx.x < nblkA) {
        src = sA; dst = dA; E = EA; nblk = nblkA; nbins = nbinsA; blk = blockIdx.x; od = offAd; os = offAs;
    } else {
        src = sB; dst = dB; E = EB; nblk = nblkB; nbins = nbinsB; blk = blockIdx.x - nblkA; od = offBd; os = offBs;
    }
    int t = threadIdx.x;
    cd[t] = 0; cs[t] = 0;
    if (t < nbins) {
        ofd[t] = ch[od + t * nblk + blk];
        ofs[t] = ch[os + t * nblk + blk];
    }
    __syncthreads();
    int e0 = blk * EPB, e1 = min(E, e0 + EPB);
    for (int e = e0 + t; e < e1; e += 256) {
        int d = dst[e], s = src[e];
        int b = d >> BUCK_BITS;
        int r = atomicAdd(&cd[b], 1);
        binned[ofd[b] + r] = (u32)s | ((u32)(d & (BUCK - 1)) << 16);
        int b2 = s >> BUCK_BITS;
        int r2 = atomicAdd(&cs[b2], 1);
        binned[ofs[b2] + r2] = (u32)(s & (BUCK - 1));
    }
}

// ======== P4: per-bucket fine pass. dst-buckets: norm_d+rowptr+esrc; src-buckets: norm_s ========
__global__ __launch_bounds__(256) void p4K(
    const u32* __restrict__ binned, const int* __restrict__ ch,
    int nbinsA, int nblkA, int offAd, int offAs,
    int nbinsB, int nblkB, int offBd, int offBs,
    int* __restrict__ rpA, float* __restrict__ ndA, int* __restrict__ esA, int NA, int EA,
    int* __restrict__ rpB, float* __restrict__ ndB, int* __restrict__ esB, int NB, int EB,
    float* __restrict__ nsA, float* __restrict__ nsB) {
    __shared__ int cnt[BUCK], pos[BUCK], fill[BUCK];
    int bid = blockIdx.x, t = threadIdx.x;
    int ndst = nbinsA + nbinsB;
    if (bid == 0 && t == 0) { rpA[NA] = EA; rpB[NB] = EB; }
    if (bid < ndst) {
        // ---- dst bucket: full CSR ----
        int blk, offm, nblkm, N, ebase; int* rp; float* nd; int* es;
        if (bid < nbinsA) { blk = bid; offm = offAd; nblkm = nblkA; rp = rpA; nd = ndA; es = esA; N = NA; ebase = 0; }
        else { blk = bid - nbinsA; offm = offBd; nblkm = nblkB; rp = rpB; nd = ndB; es = esB; N = NB; ebase = EA; }
        int e0 = ch[offm + blk * nblkm];
        int e1 = ch[offm + (blk + 1) * nblkm];   // next bucket start (or next matrix start)
        cnt[t] = 0; fill[t] = 0;
        __syncthreads();
        for (int e = e0 + t; e < e1; e += 256) atomicAdd(&cnt[(binned[e] >> 16) & 255], 1);
        __syncthreads();
        int c = cnt[t];
        int node = (blk << BUCK_BITS) + t;
        if (node < N) nd[node] = rsqrtf((float)(c + 1));
        pos[t] = c;
        __syncthreads();
        for (int off = 1; off < 256; off <<= 1) {
            int x = (t >= off) ? pos[t - off] : 0;
            __syncthreads();
            pos[t] += x;
            __syncthreads();
        }
        int start = e0 + pos[t] - c - ebase;     // within-type CSR start
        pos[t] = start;
        if (node < N) rp[node] = start;
        __syncthreads();
        for (int e = e0 + t; e < e1; e += 256) {
            u32 w = binned[e];
            int i = (w >> 16) & 255;
            int r = atomicAdd(&fill[i], 1);
            es[pos[i] + r] = (int)(w & 0xFFFFu);
        }
    } else {
        // ---- src bucket: count only -> norm_s ----
        int b2 = bid - ndst;
        int blk, offm, nblkm, N; float* ns;
        if (b2 < nbinsA) { blk = b2; offm = offAs; nblkm = nblkA; ns = nsA; N = NA; }
        else { blk = b2 - nbinsA; offm = offBs; nblkm = nblkB; ns = nsB; N = NB; }
        int e0 = ch[offm + blk * nblkm];
        int e1 = ch[offm + (blk + 1) * nblkm];
        cnt[t] = 0;
        __syncthreads();
        for (int e = e0 + t; e < e1; e += 256) atomicAdd(&cnt[binned[e] & 255], 1);
        __syncthreads();
        int node = (blk << BUCK_BITS) + t;
        if (node < N) ns[node] = rsqrtf((float)(cnt[t] + 1));
    }
}

// ======== MFMA GEMM (f16, merged A+B): Y = f16( (X*ns) @ W ), contiguous rows ========
__global__ __launch_bounds__(256) void gemmF(
    const float* __restrict__ X32A, const f16* __restrict__ X16A, const f16* __restrict__ WtA,
    const float* __restrict__ nsA, f16* __restrict__ YA, int NA, int DA, int nblkA,
    const float* __restrict__ X32B, const f16* __restrict__ X16B, const f16* __restrict__ WtB,
    const float* __restrict__ nsB, f16* __restrict__ YB, int NB, int DB, int xf16) {
    const float* X32; const f16* X16; const f16* Wt; const float* ns; f16* Y; int N, D, bid;
    if ((int)blockIdx.x < nblkA) {
        X32 = X32A; X16 = X16A; Wt = WtA; ns = nsA; Y = YA; N = NA; D = DA; bid = blockIdx.x;
    } else {
        X32 = X32B; X16 = X16B; Wt = WtB; ns = nsB; Y = YB; N = NB; D = DB; bid = blockIdx.x - nblkA;
    }
    __shared__ f16 Xs[64 * LDSTR];
    __shared__ f16 Ws[128 * LDSTR];
    int t = threadIdx.x;
    int wv = t >> 6, lane = t & 63;
    int m = lane & 15, q = lane >> 4;
    int rowbase = bid * 64;

    floatx4 acc[8];
#pragma unroll
    for (int c = 0; c < 8; c++) acc[c] = (floatx4)(0.f);

    for (int k0 = 0; k0 < D; k0 += BK) {
        __syncthreads();
        if (xf16) {   // stage pre-scaled f16 X: plain 16B copies
            int kq = (t & 7) * 8;
            int r0 = t >> 3;
#pragma unroll
            for (int i = 0; i < 2; i++) {
                int r = r0 + i * 32;
                int grow = rowbase + r;
                f16x8 v = (f16x8)(f16)0;
                if (grow < N) v = *(const f16x8*)(X16 + (size_t)grow * D + k0 + kq);
                *(f16x8*)&Xs[r * LDSTR + kq] = v;
            }
        } else {      // stage fp32 X: fold norm_s, convert to f16
            int kq = (t & 15) * 4;
#pragma unroll
            for (int i = 0; i < 4; i++) {
                int r = (t >> 4) + i * 16;
                int grow = rowbase + r;
                float4 v = make_float4(0.f, 0.f, 0.f, 0.f);
                float nv = 0.f;
                if (grow < N) {
                    v = *(const float4*)(X32 + (size_t)grow * D + k0 + kq);
                    nv = ns[grow];
                }
                f16x4 hv;
                hv[0] = (f16)(v.x * nv); hv[1] = (f16)(v.y * nv);
                hv[2] = (f16)(v.z * nv); hv[3] = (f16)(v.w * nv);
                *(f16x4*)&Xs[r * LDSTR + kq] = hv;
            }
        }
        {   // stage W chunk: 128 c x 64 k
            int ks = (t & 7) * 8;
            int rb = t >> 3;
#pragma unroll
            for (int i = 0; i < 4; i++) {
                int c = rb + i * 32;
                *(f16x8*)&Ws[c * LDSTR + ks] = *(const f16x8*)&Wt[(size_t)c * D + k0 + ks];
            }
        }
        __syncthreads();
#pragma unroll
        for (int ks = 0; ks < BK; ks += 32) {
            f16x8 a = *(const f16x8*)&Xs[(wv * 16 + m) * LDSTR + ks + q * 8];
#pragma unroll
            for (int c = 0; c < 8; c++) {
                f16x8 b = *(const f16x8*)&Ws[(c * 16 + m) * LDSTR + ks + q * 8];
                acc[c] = __builtin_amdgcn_mfma_f32_16x16x32_f16(a, b, acc[c], 0, 0, 0);
            }
        }
    }
    // D layout col=lane&15, row=(lane>>4)*4+reg ; contiguous f16 row store
#pragma unroll
    for (int c = 0; c < 8; c++)
#pragma unroll
        for (int r = 0; r < 4; r++) {
            int grow = rowbase + wv * 16 + q * 4 + r;
            if (grow < N) Y[(size_t)grow * H + c * 16 + m] = (f16)acc[c][r];
        }
}

// ======== aggregation v4: 1 node per 8-lane subgroup, 4 edges/round, index prefetch ========
__global__ __launch_bounds__(256) void aggC(
    const f16* __restrict__ YA, const int* __restrict__ rpA, const int* __restrict__ esA,
    const float* __restrict__ ndA, const float* __restrict__ nsA, const float* __restrict__ bA,
    float* __restrict__ oA, f16* __restrict__ hA, int nA32, int NA,
    const f16* __restrict__ YB, const int* __restrict__ rpB, const int* __restrict__ esB,
    const float* __restrict__ ndB, const float* __restrict__ nsB, const float* __restrict__ bB,
    float* __restrict__ oB, f16* __restrict__ hB, int NB, int layer0) {
    const f16* Y; const int *rp, *es; const float *nd, *ns, *bias; float* out; f16* hout;
    int N, blk;
    if ((int)blockIdx.x < nA32) {
        Y = YA; rp = rpA; es = esA; nd = ndA; ns = nsA; bias = bA; out = oA; hout = hA;
        N = NA; blk = blockIdx.x;
    } else {
        Y = YB; rp = rpB; es = esB; nd = ndB; ns = nsB; bias = bB; out = oB; hout = hB;
        N = NB; blk = blockIdx.x - nA32;
    }
    int t = threadIdx.x;
    int slot = t >> 3;
    int d = t & 7;
    int node = blk * 32 + slot;
    bool act = node < N;
    int nc = act ? node : (N - 1);
    int beg = rp[nc];
    int cnt = act ? (rp[nc + 1] - beg) : 0;
    int tot = cnt + 1;
    const f16* Yd = Y + (size_t)d * 16;
    float acc[16];
#pragma unroll
    for (int i = 0; i < 16; i++) acc[i] = 0.f;
    int i0 = (0 < cnt) ? es[beg]     : nc;
    int i1 = (1 < cnt) ? es[beg + 1] : nc;
    int i2 = (2 < cnt) ? es[beg + 2] : nc;
    int i3 = (3 < cnt) ? es[beg + 3] : nc;
    int j = 0;
    for (; j + 4 <= tot; j += 4) {
        f16x8 a0 = *(const f16x8*)(Yd + (size_t)i0 * H);
        f16x8 b0 = *(const f16x8*)(Yd + (size_t)i0 * H + 8);
        f16x8 a1 = *(const f16x8*)(Yd + (size_t)i1 * H);
        f16x8 b1 = *(const f16x8*)(Yd + (size_t)i1 * H + 8);
        f16x8 a2 = *(const f16x8*)(Yd + (size_t)i2 * H);
        f16x8 b2 = *(const f16x8*)(Yd + (size_t)i2 * H + 8);
        f16x8 a3 = *(const f16x8*)(Yd + (size_t)i3 * H);
        f16x8 b3 = *(const f16x8*)(Yd + (size_t)i3 * H + 8);
        int jn = j + 4;
        int n0 = (jn     < cnt) ? es[beg + jn]     : nc;
        int n1 = (jn + 1 < cnt) ? es[beg + jn + 1] : nc;
        int n2 = (jn + 2 < cnt) ? es[beg + jn + 2] : nc;
        int n3 = (jn + 3 < cnt) ? es[beg + jn + 3] : nc;
#pragma unroll
        for (int i = 0; i < 8; i++) {
            acc[i]     += ((float)a0[i] + (float)a1[i]) + ((float)a2[i] + (float)a3[i]);
            acc[i + 8] += ((float)b0[i] + (float)b1[i]) + ((float)b2[i] + (float)b3[i]);
        }
        i0 = n0; i1 = n1; i2 = n2; i3 = n3;
    }
    int rem = tot - j;
    if (rem > 0) {
        f16x8 a0 = *(const f16x8*)(Yd + (size_t)i0 * H);
        f16x8 b0 = *(const f16x8*)(Yd + (size_t)i0 * H + 8);
        if (rem > 1) {
            f16x8 a1 = *(const f16x8*)(Yd + (size_t)i1 * H);
            f16x8 b1 = *(const f16x8*)(Yd + (size_t)i1 * H + 8);
            if (rem > 2) {
                f16x8 a2 = *(const f16x8*)(Yd + (size_t)i2 * H);
                f16x8 b2 = *(const f16x8*)(Yd + (size_t)i2 * H + 8);
#pragma unroll
                for (int i = 0; i < 8; i++) {
                    acc[i]     += ((float)a0[i] + (float)a1[i]) + (float)a2[i];
                    acc[i + 8] += ((float)b0[i] + (float)b1[i]) + (float)b2[i];
                }
            } else {
#pragma unroll
                for (int i = 0; i < 8; i++) {
                    acc[i]     += (float)a0[i] + (float)a1[i];
                    acc[i + 8] += (float)b0[i] + (float)b1[i];
                }
            }
        } else {
#pragma unroll
            for (int i = 0; i < 8; i++) {
                acc[i]     += (float)a0[i];
                acc[i + 8] += (float)b0[i];
            }
        }
    }
    if (act) {
        float ndv = nd[node];
        float4 c0 = *(const float4*)(bias + d * 16);
        float4 c1 = *(const float4*)(bias + d * 16 + 4);
        float4 c2 = *(const float4*)(bias + d * 16 + 8);
        float4 c3 = *(const float4*)(bias + d * 16 + 12);
        float o_[16];
        o_[0]  = fmaf(acc[0],  ndv, c0.x); o_[1]  = fmaf(acc[1],  ndv, c0.y);
        o_[2]  = fmaf(acc[2],  ndv, c0.z); o_[3]  = fmaf(acc[3],  ndv, c0.w);
        o_[4]  = fmaf(acc[4],  ndv, c1.x); o_[5]  = fmaf(acc[5],  ndv, c1.y);
        o_[6]  = fmaf(acc[6],  ndv, c1.z); o_[7]  = fmaf(acc[7],  ndv, c1.w);
        o_[8]  = fmaf(acc[8],  ndv, c2.x); o_[9]  = fmaf(acc[9],  ndv, c2.y);
        o_[10] = fmaf(acc[10], ndv, c2.z); o_[11] = fmaf(acc[11], ndv, c2.w);
        o_[12] = fmaf(acc[12], ndv, c3.x); o_[13] = fmaf(acc[13], ndv, c3.y);
        o_[14] = fmaf(acc[14], ndv, c3.z); o_[15] = fmaf(acc[15], ndv, c3.w);
        if (layer0) {
            float nsv = ns[node];
            f16x8 h0, h1;
#pragma unroll
            for (int i = 0; i < 8; i++) {
                h0[i] = (f16)(fmaxf(o_[i], 0.f) * nsv);
                h1[i] = (f16)(fmaxf(o_[i + 8], 0.f) * nsv);
            }
            *(f16x8*)(hout + (size_t)node * H + d * 16) = h0;
            *(f16x8*)(hout + (size_t)node * H + d * 16 + 8) = h1;
        } else {
            float* op = out + (size_t)node * H + d * 16;
            *(float4*)op       = make_float4(o_[0],  o_[1],  o_[2],  o_[3]);
            *(float4*)(op + 4) = make_float4(o_[4],  o_[5],  o_[6],  o_[7]);
            *(float4*)(op + 8) = make_float4(o_[8],  o_[9],  o_[10], o_[11]);
            *(float4*)(op + 12)= make_float4(o_[12], o_[13], o_[14], o_[15]);
        }
    }
}

// ---------------- host ----------------

struct TypeBufs {
    int *rowptr, *esrc;
    float *norm_s, *norm_d;
    f16 *h, *y, *wt0, *wt1;
};

extern "C" void kernel_launch(void* const* d_in, const int* in_sizes, int n_in,
                              void* d_out, int out_size, void* d_ws, size_t ws_size,
                              hipStream_t stream) {
    (void)n_in; (void)out_size; (void)ws_size;
    const float* feat_a = (const float*)d_in[0];
    const float* feat_b = (const float*)d_in[1];
    const int* src_a = (const int*)d_in[2];
    const int* dst_a = (const int*)d_in[3];
    const int* src_b = (const int*)d_in[4];
    const int* dst_b = (const int*)d_in[5];
    const float* Wa0 = (const float*)d_in[6];
    const float* ba0 = (const float*)d_in[7];
    const float* Wa1 = (const float*)d_in[8];
    const float* ba1 = (const float*)d_in[9];
    const float* Wb0 = (const float*)d_in[10];
    const float* bb0 = (const float*)d_in[11];
    const float* Wb1 = (const float*)d_in[12];
    const float* bb1 = (const float*)d_in[13];

    const int DA = in_sizes[6] / H;   // 256
    const int DB = in_sizes[10] / H;  // 128
    const int NA = in_sizes[0] / DA;  // 50000
    const int NB = in_sizes[1] / DB;  // 30000
    const int EA = in_sizes[2];       // 600000
    const int EB = in_sizes[4];       // 300000

    const int nblkA = ceil_div(EA, EPB), nblkB = ceil_div(EB, EPB);
    const int nbinsA = ceil_div(NA, BUCK), nbinsB = ceil_div(NB, BUCK);
    const int LAd = nbinsA * nblkA, LBd = nbinsB * nblkB;
    const int offAd = 0;
    const int offBd = LAd;
    const int offAs = offBd + LBd;
    const int offBs = offAs + LAd;
    const int Lall = offBs + LBd;

    char* w = (char*)d_ws;
    auto carve = [&](size_t bytes) {
        void* p = (void*)w;
        w += (bytes + 255) & ~(size_t)255;
        return p;
    };
    int* ch = (int*)carve(((size_t)Lall + 1) * 4);
    int* bsum = (int*)carve(256 * 4);
    u32* binned = (u32*)carve((size_t)2 * (EA + EB) * 4);
    auto carve_type = [&](int N, int E, int D) {
        TypeBufs tb;
        tb.rowptr = (int*)carve(((size_t)N + 1) * 4);
        tb.esrc   = (int*)carve((size_t)E * 4);
        tb.norm_s = (float*)carve((size_t)N * 4);
        tb.norm_d = (float*)carve((size_t)N * 4);
        tb.h      = (f16*)carve((size_t)N * H * 2);
        tb.y      = (f16*)carve((size_t)N * H * 2);
        tb.wt0    = (f16*)carve((size_t)D * H * 2);
        tb.wt1    = (f16*)carve((size_t)H * H * 2);
        return tb;
    };
    TypeBufs A = carve_type(NA, EA, DA);
    TypeBufs B = carve_type(NB, EB, DB);

    float* out_a = (float*)d_out;
    float* out_b = out_a + (size_t)NA * H;

    const int gblkA = ceil_div(NA, 64), gblkB = ceil_div(NB, 64);
    const int nA32 = ceil_div(NA, 32), nB32 = ceil_div(NB, 32);
    const int wcBlocks = (DA + 3 * H) / 2;
    const int nScan = Lall + 1;
    const int sb1 = ceil_div(nScan, 1024);

    // ---- prep: 5 launches, all wide-parallel ----
    p1K<<<nblkA + nblkB + wcBlocks, 256, 0, stream>>>(
        src_a, dst_a, EA, nblkA, nbinsA, src_b, dst_b, EB, nblkB, nbinsB,
        ch, offAd, offBd, offAs, offBs, Lall,
        Wa0, A.wt0, Wa1, A.wt1, Wb0, B.wt0, Wb1, B.wt1, DA);
    scan1K<<<sb1, 256, 0, stream>>>(ch, nScan, bsum);
    scan23K<<<ceil_div(nScan, 256), 256, 0, stream>>>(ch, bsum, sb1, nScan);
    p3K<<<nblkA + nblkB, 256, 0, stream>>>(
        src_a, dst_a, EA, nblkA, nbinsA, src_b, dst_b, EB, nblkB, nbinsB,
        ch, offAd, offBd, offAs, offBs, binned);
    p4K<<<2 * (nbinsA + nbinsB), 256, 0, stream>>>(
        binned, ch, nbinsA, nblkA, offAd, offAs, nbinsB, nblkB, offBd, offBs,
        A.rowptr, A.norm_d, A.esrc, NA, EA,
        B.rowptr, B.norm_d, B.esrc, NB, EB,
        A.norm_s, B.norm_s);
    // ---- layer 0 ----
    gemmF<<<gblkA + gblkB, 256, 0, stream>>>(
        feat_a, (const f16*)nullptr, A.wt0, A.norm_s, A.y, NA, DA, gblkA,
        feat_b, (const f16*)nullptr, B.wt0, B.norm_s, B.y, NB, DB, 0);
    aggC<<<nA32 + nB32, 256, 0, stream>>>(
        A.y, A.rowptr, A.esrc, A.norm_d, A.norm_s, ba0, out_a, A.h, nA32, NA,
        B.y, B.rowptr, B.esrc, B.norm_d, B.norm_s, bb0, out_b, B.h, NB, 1);
    // ---- layer 1 ----
    gemmF<<<gblkA + gblkB, 256, 0, stream>>>(
        (const float*)nullptr, A.h, A.wt1, A.norm_s, A.y, NA, H, gblkA,
        (const float*)nullptr, B.h, B.wt1, B.norm_s, B.y, NB, H, 1);
    aggC<<<nA32 + nB32, 256, 0, stream>>>(
        A.y, A.rowptr, A.esrc, A.norm_d, A.norm_s, ba1, out_a, A.h, nA32, NA,
        B.y, B.rowptr, B.esrc, B.norm_d, B.norm_s, bb1, out_b, B.h, NB, 0);
}